// Round 1
// baseline (250.990 us; speedup 1.0000x reference)
//
#include <hip/hip_runtime.h>
#include <hip/hip_bf16.h>

#define N 8192
#define D 256
#define NSLICE 4
#define BM 128                       // rows per block (4 waves x 32 rows)
#define COLS_PER_SLICE (N / NSLICE)  // 2048

typedef __attribute__((ext_vector_type(8))) short bf16x8;
typedef __attribute__((ext_vector_type(4))) float f32x4;

__device__ inline ushort f2bf(float x) {
    __hip_bfloat16 h = __float2bfloat16(x);
    return *reinterpret_cast<ushort*>(&h);
}

// ---------------- kernel 0: fp32 -> bf16 conversion ----------------
__global__ void convert_bf16(const float* __restrict__ F, const float* __restrict__ Imp,
                             ushort* __restrict__ Fb, ushort* __restrict__ Ib) {
    const int i = blockIdx.x * blockDim.x + threadIdx.x;  // float4 index
    const int total4 = N * D / 4;
    const float4* src = (blockIdx.y == 0) ? (const float4*)F : (const float4*)Imp;
    ushort* dst = (blockIdx.y == 0) ? Fb : Ib;
    if (i < total4) {
        float4 v = src[i];
        ushort4 o;
        o.x = f2bf(v.x); o.y = f2bf(v.y); o.z = f2bf(v.z); o.w = f2bf(v.w);
        *reinterpret_cast<ushort4*>(dst + 4 * (size_t)i) = o;
    }
}

// ---------------- kernel 1: fused MFMA + mask + online row-LSE ----------------
// blockIdx.x: row block (BM rows), blockIdx.y: column slice, blockIdx.z: pass
// pass 0: A=F, B=I  (row direction);  pass 1: A=I, B=F (col direction, mask symmetric)
__launch_bounds__(256)
__global__ void lse_partial(const ushort* __restrict__ Fb, const ushort* __restrict__ Ib,
                            const int* __restrict__ labels, float2* __restrict__ partials) {
    const int pass = blockIdx.z;
    const ushort* A = pass ? Ib : Fb;
    const ushort* B = pass ? Fb : Ib;

    const int lane = threadIdx.x & 63;
    const int wave = threadIdx.x >> 6;
    const int row0 = blockIdx.x * BM + wave * 32;  // 2 row-tiles of 16
    const int c0 = blockIdx.y * COLS_PER_SLICE;

    const int lrow = lane & 15;   // A row within tile / B col within tile
    const int kgrp = lane >> 4;   // 0..3

    // A fragments: lane holds A[row0+t*16+lrow][ks*32 + kgrp*8 + j], j=0..7
    bf16x8 afrag[2][8];
#pragma unroll
    for (int t = 0; t < 2; ++t) {
        const ushort* arow = A + (size_t)(row0 + t * 16 + lrow) * D;
#pragma unroll
        for (int ks = 0; ks < 8; ++ks)
            afrag[t][ks] = *reinterpret_cast<const bf16x8*>(arow + ks * 32 + kgrp * 8);
    }

    // labels of my output rows: row = row0 + t*16 + kgrp*4 + r
    int labr[2][4];
#pragma unroll
    for (int t = 0; t < 2; ++t)
#pragma unroll
        for (int r = 0; r < 4; ++r)
            labr[t][r] = labels[row0 + t * 16 + kgrp * 4 + r];

    float m[2][4], s[2][4];
#pragma unroll
    for (int t = 0; t < 2; ++t)
#pragma unroll
        for (int r = 0; r < 4; ++r) { m[t][r] = -3.0e38f; s[t][r] = 0.0f; }

    for (int ct = 0; ct < COLS_PER_SLICE / 16; ++ct) {
        const int col0 = c0 + ct * 16;
        const int mycol = col0 + lrow;
        const int labc = labels[mycol];
        const ushort* brow = B + (size_t)mycol * D;
        bf16x8 bfrag[8];
#pragma unroll
        for (int ks = 0; ks < 8; ++ks)
            bfrag[ks] = *reinterpret_cast<const bf16x8*>(brow + ks * 32 + kgrp * 8);

#pragma unroll
        for (int t = 0; t < 2; ++t) {
            f32x4 acc = {0.f, 0.f, 0.f, 0.f};
#pragma unroll
            for (int ks = 0; ks < 8; ++ks)
                acc = __builtin_amdgcn_mfma_f32_16x16x32_bf16(afrag[t][ks], bfrag[ks], acc, 0, 0, 0);

            // D layout: col = lane&15, row = (lane>>4)*4 + r   [HW-verified]
#pragma unroll
            for (int r = 0; r < 4; ++r) {
                float l = acc[r] * 2.0f;  // temperature 0.5
                const int grow = row0 + t * 16 + kgrp * 4 + r;
                const bool msk = (labr[t][r] == labc) && (grow != mycol);
                l = msk ? 0.0f : l;
                // online LSE, single-exp fast path
                if (l <= m[t][r]) {
                    s[t][r] += __expf(l - m[t][r]);
                } else {
                    s[t][r] = s[t][r] * __expf(m[t][r] - l) + 1.0f;
                    m[t][r] = l;
                }
            }
        }
    }

    // merge the 16 lanes (same rows, disjoint column subsequences)
#pragma unroll
    for (int off = 1; off < 16; off <<= 1) {
#pragma unroll
        for (int t = 0; t < 2; ++t)
#pragma unroll
            for (int r = 0; r < 4; ++r) {
                float om = __shfl_xor(m[t][r], off, 64);
                float os = __shfl_xor(s[t][r], off, 64);
                float M = fmaxf(m[t][r], om);
                s[t][r] = s[t][r] * __expf(m[t][r] - M) + os * __expf(om - M);
                m[t][r] = M;
            }
    }

    if (lrow == 0) {
#pragma unroll
        for (int t = 0; t < 2; ++t)
#pragma unroll
            for (int r = 0; r < 4; ++r) {
                const int grow = row0 + t * 16 + kgrp * 4 + r;
                partials[((size_t)pass * N + grow) * NSLICE + blockIdx.y] =
                    make_float2(m[t][r], s[t][r]);
            }
    }
}

// ---------------- kernel 2: per-row contribution (wave per row) ----------------
__global__ void row_contrib(const float* __restrict__ F, const float* __restrict__ Imp,
                            const float2* __restrict__ partials, float* __restrict__ blockSums) {
    const int lane = threadIdx.x & 63;
    const int wave = threadIdx.x >> 6;
    const int row = blockIdx.x * 4 + wave;

    // fp32 diagonal dot: 256 floats = 64 lanes * float4
    float4 a = reinterpret_cast<const float4*>(F + (size_t)row * D)[lane];
    float4 b = reinterpret_cast<const float4*>(Imp + (size_t)row * D)[lane];
    float dot = a.x * b.x + a.y * b.y + a.z * b.z + a.w * b.w;
#pragma unroll
    for (int off = 32; off > 0; off >>= 1) dot += __shfl_xor(dot, off, 64);

    __shared__ float sums[4];
    if (lane == 0) {
        float lse_total = 0.0f;
#pragma unroll
        for (int pass = 0; pass < 2; ++pass) {
            float M = -3.0e38f, S = 0.0f;
#pragma unroll
            for (int k = 0; k < NSLICE; ++k) {
                float2 p = partials[((size_t)pass * N + row) * NSLICE + k];
                float nm = fmaxf(M, p.x);
                S = S * __expf(M - nm) + p.y * __expf(p.x - nm);
                M = nm;
            }
            lse_total += M + __logf(S);
        }
        // contribution = 2*diag - lse_row - lse_col, diag = 2*dot
        sums[wave] = 4.0f * dot - lse_total;
    }
    __syncthreads();
    if (threadIdx.x == 0)
        blockSums[blockIdx.x] = sums[0] + sums[1] + sums[2] + sums[3];
}

// ---------------- kernel 3: final deterministic reduce ----------------
__global__ void final_reduce(const float* __restrict__ blockSums, float* __restrict__ out) {
    __shared__ float red[256];
    float v = 0.0f;
    for (int i = threadIdx.x; i < N / 4; i += 256) v += blockSums[i];
    red[threadIdx.x] = v;
    __syncthreads();
    for (int st = 128; st > 0; st >>= 1) {
        if (threadIdx.x < st) red[threadIdx.x] += red[threadIdx.x + st];
        __syncthreads();
    }
    if (threadIdx.x == 0) out[0] = -red[0] / (float)N;
}

extern "C" void kernel_launch(void* const* d_in, const int* in_sizes, int n_in,
                              void* d_out, int out_size, void* d_ws, size_t ws_size,
                              hipStream_t stream) {
    const float* F = (const float*)d_in[0];
    const float* Imp = (const float*)d_in[1];
    const int* labels = (const int*)d_in[2];
    float* out = (float*)d_out;

    char* ws = (char*)d_ws;
    ushort* Fb = (ushort*)ws;                                   // 4 MB
    ushort* Ib = (ushort*)(ws + (size_t)4 * 1024 * 1024);       // 4 MB
    float2* partials = (float2*)(ws + (size_t)8 * 1024 * 1024); // 512 KB
    float* blockSums = (float*)(ws + (size_t)8 * 1024 * 1024 + 512 * 1024);  // 8 KB

    dim3 cgrid((N * D / 4 + 255) / 256, 2);
    convert_bf16<<<cgrid, 256, 0, stream>>>(F, Imp, Fb, Ib);

    dim3 g(N / BM, NSLICE, 2);
    lse_partial<<<g, 256, 0, stream>>>(Fb, Ib, labels, partials);

    row_contrib<<<N / 4, 256, 0, stream>>>(F, Imp, partials, blockSums);
    final_reduce<<<1, 256, 0, stream>>>(blockSums, out);
}